// Round 2
// baseline (167.395 us; speedup 1.0000x reference)
//
#include <hip/hip_runtime.h>

typedef _Float16 f16;
typedef _Float16 f16x4 __attribute__((ext_vector_type(4)));
typedef _Float16 f16x8 __attribute__((ext_vector_type(8)));
typedef float    f32x4 __attribute__((ext_vector_type(4)));

#define NB   8
#define TE   2048
#define TD   2048
#define DIM  256
#define NSPLIT 3
#define LOG2E 1.44269504088896340736f

#define AS1(p) ((const __attribute__((address_space(1))) void*)(p))
#define AS3(p) ((__attribute__((address_space(3))) void*)(p))
#define MFMA16(a,b,c) __builtin_amdgcn_mfma_f32_16x16x32_f16((a),(b),(c),0,0,0)

// ---------------- prep: enc fp32 -> f16, same layout ----------------
__global__ __launch_bounds__(256) void prep_kernel(const float* __restrict__ enc,
                                                   f16* __restrict__ ench) {
    size_t i = ((size_t)blockIdx.x * 256 + threadIdx.x) * 8;
    float4 v0 = *(const float4*)(enc + i);
    float4 v1 = *(const float4*)(enc + i + 4);
    f16x8 o;
    o[0]=(f16)v0.x; o[1]=(f16)v0.y; o[2]=(f16)v0.z; o[3]=(f16)v0.w;
    o[4]=(f16)v1.x; o[5]=(f16)v1.y; o[6]=(f16)v1.z; o[7]=(f16)v1.w;
    *(f16x8*)(ench + i) = o;
}

// ---------------- fused attention, symmetric 4-wave, single staged enc tile ----------------
// Identical to round-1 EXCEPT the PV A-fragment fetch: plain ds_read_u16 gathers
// (8 per fragment) instead of ds_read_b64_tr_b16 + inline-asm waits. Bisection round:
// isolates {tr-read semantics, asm scheduling} as the suspected round-1 bug.
// Subtiled layout: half(e,d) = ((e>>2)*16 + (d>>4))*64 + (e&3)*16 + (d&15)
//   QK reads rows via ds_read_b128; PV gathers columns via ds_read_u16.
// LDS 38,400 B -> 3 blocks/CU (12 waves/CU).
#define LDS_P  32768
#define LDS_X  37888

__global__ __launch_bounds__(256, 3) void attn_kernel(
        const float* __restrict__ dec32,
        const f16*  __restrict__ enc_h,
        f16*   __restrict__ ctxp,
        float* __restrict__ m_arr,
        float* __restrict__ l_arr,
        int nsplit) {
    __shared__ __align__(16) char lds[38400];
    const int tid  = threadIdx.x;
    const int lane = tid & 63;
    const int wv   = tid >> 6;
    const int th   = wv >> 1;
    const int eh   = wv & 1;
    const int tcol = lane & 15;
    const int q    = lane >> 4;

    int fid = blockIdx.x + 32 * (blockIdx.y + 8 * blockIdx.z);
    const int b  = fid & 7;
    const int xb = (fid >> 3) & 31;
    const int z  = fid >> 8;
    const int t0 = xb * 64;
    const int tile0 = (64 * z) / nsplit;
    const int tile1 = (64 * (z + 1)) / nsplit;
    const int iters = tile1 - tile0;

    const char* encb = (const char*)(enc_h + (size_t)b * TE * DIM);

    // staging: chunk c = i*256 + wv*64 + lane (16B); inverse subtile map
    const int c0  = wv * 64 + lane;
    const int e_l = ((c0 >> 7) << 2) | ((c0 >> 1) & 3);
    const int d_l = (((c0 >> 3) & 15) << 4) | ((c0 & 1) << 3);
    const int stage_goff = e_l * (DIM * 2) + d_l * 2;
    char* stage_dst = lds + wv * 1024;

    // QK row read: e = eh*16+tcol, d-octet = ks*32+q*8
    const int qk_base = (eh * 4 + (tcol >> 2)) * 2048 + (q >> 1) * 128 + (tcol & 3) * 32 + (q & 1) * 16;
    // PV gather base: d = eh*128 + dm*16 + tcol, e = q*8+j
    //   byte(e,d) = q*4096 + eh*1024 + dm*128 + tcol*2  (+ j*32 ; j>=4: +2048)
    const int pv_base = q * 4096 + eh * 1024 + tcol * 2;
    char* pb = lds + LDS_P + th * 2560;           // P: 32 rows x 80 B
    float* exch = (float*)(lds + LDS_X);          // 4 waves x 32 floats

    // Q fragments: B[k=d][n=t]
    f16x8 qf[2][8];
    {
        const float* qp = dec32 + ((size_t)b * TD + t0 + th * 32) * DIM;
        #pragma unroll
        for (int tn = 0; tn < 2; tn++)
            #pragma unroll
            for (int ks = 0; ks < 8; ks++) {
                const float* p = qp + (size_t)(tn * 16 + tcol) * DIM + ks * 32 + q * 8;
                float4 u = *(const float4*)(p);
                float4 v = *(const float4*)(p + 4);
                f16x8 o;
                o[0]=(f16)u.x; o[1]=(f16)u.y; o[2]=(f16)u.z; o[3]=(f16)u.w;
                o[4]=(f16)v.x; o[5]=(f16)v.y; o[6]=(f16)v.z; o[7]=(f16)v.w;
                qf[tn][ks] = o;
            }
    }

    { // stage tile0 -> buf0
        const char* s = encb + (size_t)tile0 * 16384 + stage_goff;
        #pragma unroll
        for (int i = 0; i < 4; i++)
            __builtin_amdgcn_global_load_lds(AS1(s + i * 4096), AS3(stage_dst + i * 4096), 16, 0, 0);
    }

    const f32x4 zero4 = {0.f, 0.f, 0.f, 0.f};
    float m_[2] = {-INFINITY, -INFINITY};
    float l_[2] = {0.f, 0.f};
    f32x4 ctx[8][2];
    #pragma unroll
    for (int dm = 0; dm < 8; dm++) { ctx[dm][0] = zero4; ctx[dm][1] = zero4; }

    __syncthreads();   // NAT(0) staged & drained

    for (int it = 0; it < iters; ++it) {
        const int nat = (it & 1) << 14;
        // ---- W1: QK quadrant (e16 x t32) ----
        f32x4 st[2] = {zero4, zero4};
        const char* natp = lds + nat + qk_base;
        #pragma unroll
        for (int ks = 0; ks < 8; ks++) {
            f16x8 af = *(const f16x8*)(natp + ks * 256);
            st[0] = MFMA16(af, qf[0][ks], st[0]);
            st[1] = MFMA16(af, qf[1][ks], st[1]);
        }
        float mx[2];
        #pragma unroll
        for (int tn = 0; tn < 2; tn++) {
            float m0 = fmaxf(fmaxf(st[tn][0], st[tn][1]), fmaxf(st[tn][2], st[tn][3]));
            m0 = fmaxf(m0, __shfl_xor(m0, 16, 64));
            m0 = fmaxf(m0, __shfl_xor(m0, 32, 64));
            mx[tn] = m0;
        }
        if (q == 0) { exch[wv * 32 + tcol] = mx[0]; exch[wv * 32 + 16 + tcol] = mx[1]; }
        __syncthreads();   // bar1
        // ---- W2 ----
        if (it + 1 < iters) {   // stage next tile early; drained at bar2
            const char* s = encb + (size_t)(tile0 + it + 1) * 16384 + stage_goff;
            char* dd = stage_dst + (((it + 1) & 1) << 14);
            #pragma unroll
            for (int i = 0; i < 4; i++)
                __builtin_amdgcn_global_load_lds(AS1(s + i * 4096), AS3(dd + i * 4096), 16, 0, 0);
        }
        bool anyb = false;
        float al[2], s4v[2];
        #pragma unroll
        for (int tn = 0; tn < 2; tn++) {
            float ox = exch[(wv ^ 1) * 32 + tn * 16 + tcol];
            float mn = fmaxf(m_[tn], fmaxf(mx[tn], ox));
            al[tn] = __builtin_amdgcn_exp2f((m_[tn] - mn) * LOG2E);
            anyb = anyb || (mn > m_[tn]);
            m_[tn] = mn;
            f16x4 pv;
            #pragma unroll
            for (int r = 0; r < 4; r++)
                pv[r] = (f16)__builtin_amdgcn_exp2f((st[tn][r] - mn) * LOG2E);
            *(f16x4*)(pb + (tn * 16 + tcol) * 80 + eh * 32 + q * 8) = pv;
            float s4 = ((float)pv[0] + (float)pv[1]) + ((float)pv[2] + (float)pv[3]);
            s4 += __shfl_xor(s4, 16, 64);
            s4 += __shfl_xor(s4, 32, 64);
            s4v[tn] = s4;
        }
        if (__any(anyb)) {
            #pragma unroll
            for (int tn = 0; tn < 2; tn++) {
                l_[tn] *= al[tn];
                #pragma unroll
                for (int dm = 0; dm < 8; dm++) {
                    ctx[dm][tn][0] *= al[tn]; ctx[dm][tn][1] *= al[tn];
                    ctx[dm][tn][2] *= al[tn]; ctx[dm][tn][3] *= al[tn];
                }
            }
        }
        l_[0] += s4v[0]; l_[1] += s4v[1];
        __syncthreads();   // bar2: P visible, stage(it+1) drained
        // ---- C: PV (d-half 128 x t32); A-fragments via plain u16 gathers ----
        f16x8 pf0 = *(const f16x8*)(pb + tcol * 80 + q * 16);
        f16x8 pf1 = *(const f16x8*)(pb + (16 + tcol) * 80 + q * 16);
        const char* trp = lds + nat + pv_base;
        #pragma unroll
        for (int dm = 0; dm < 8; dm++) {
            const char* base = trp + dm * 128;
            f16x8 af;
            #pragma unroll
            for (int j = 0; j < 4; j++) {
                af[j]     = *(const f16*)(base + j * 32);          // e = q*8 + j
                af[j + 4] = *(const f16*)(base + 2048 + j * 32);   // e = q*8 + 4 + j
            }
            ctx[dm][0] = MFMA16(af, pf0, ctx[dm][0]);
            ctx[dm][1] = MFMA16(af, pf1, ctx[dm][1]);
        }
        // no barrier: C merges into next W1 (different NAT buffer, P protected by bar1)
    }

    // ---- epilogue: merge l across eh-partners, write normalized f16 partials ----
    if (q == 0) { exch[wv * 32 + tcol] = l_[0]; exch[wv * 32 + 16 + tcol] = l_[1]; }
    __syncthreads();
    float lt[2];
    lt[0] = l_[0] + exch[(wv ^ 1) * 32 + tcol];
    lt[1] = l_[1] + exch[(wv ^ 1) * 32 + 16 + tcol];
    size_t row0 = (size_t)(z * NB + b) * TD + t0 + th * 32;
    #pragma unroll
    for (int tn = 0; tn < 2; tn++) {
        float inv = 1.0f / lt[tn];
        size_t rb = (row0 + tn * 16 + tcol) * DIM + eh * 128;
        #pragma unroll
        for (int dm = 0; dm < 8; dm++) {
            f16x4 cv;
            #pragma unroll
            for (int r = 0; r < 4; r++) cv[r] = (f16)(ctx[dm][tn][r] * inv);
            *(f16x4*)(ctxp + rb + dm * 16 + q * 4) = cv;
        }
    }
    if (eh == 0 && q == 0) {
        int mi = (z * NB + b) * TD + t0 + th * 32 + tcol;
        m_arr[mi]      = m_[0];
        m_arr[mi + 16] = m_[1];
        l_arr[mi]      = lt[0];
        l_arr[mi + 16] = lt[1];
    }
}

// ---------------- combine: merge nsplit normalized partials + decoder passthrough ----------
__global__ __launch_bounds__(256) void combine_kernel(const float* __restrict__ dec32,
        const f16* __restrict__ ctxp, const float* __restrict__ m_arr,
        const float* __restrict__ l_arr, float* __restrict__ out, int nsplit) {
    int idx  = blockIdx.x * 256 + threadIdx.x;
    int trow = idx >> 5;              // b*TD + t
    int dg   = (idx & 31) * 8;
    float m0[NSPLIT], l0[NSPLIT], M = -INFINITY;
    #pragma unroll
    for (int s = 0; s < NSPLIT; s++) if (s < nsplit) {
        m0[s] = m_arr[s * (NB * TD) + trow];
        l0[s] = l_arr[s * (NB * TD) + trow];
        M = fmaxf(M, m0[s]);
    }
    float L = 0.f, w[NSPLIT];
    #pragma unroll
    for (int s = 0; s < NSPLIT; s++) if (s < nsplit) {
        w[s] = __builtin_amdgcn_exp2f((m0[s] - M) * LOG2E) * l0[s];
        L += w[s];
    }
    float invL = 1.0f / L;
    float acc[8] = {0.f,0.f,0.f,0.f,0.f,0.f,0.f,0.f};
    #pragma unroll
    for (int s = 0; s < NSPLIT; s++) if (s < nsplit) {
        f16x8 v = *(const f16x8*)(ctxp + ((size_t)s * (NB * TD) + trow) * DIM + dg);
        float ws = w[s] * invL;
        #pragma unroll
        for (int j = 0; j < 8; j++) acc[j] += ws * (float)v[j];
    }
    float4 d0 = *(const float4*)(dec32 + (size_t)trow * DIM + dg);
    float4 d1 = *(const float4*)(dec32 + (size_t)trow * DIM + dg + 4);
    float* ob = out + (size_t)trow * 512;
    *(float4*)(ob + dg)     = d0;
    *(float4*)(ob + dg + 4) = d1;
    float4 c0, c1;
    c0.x=acc[0]; c0.y=acc[1]; c0.z=acc[2]; c0.w=acc[3];
    c1.x=acc[4]; c1.y=acc[5]; c1.z=acc[6]; c1.w=acc[7];
    *(float4*)(ob + 256 + dg)     = c0;
    *(float4*)(ob + 256 + dg + 4) = c1;
}

extern "C" void kernel_launch(void* const* d_in, const int* in_sizes, int n_in,
                              void* d_out, int out_size, void* d_ws, size_t ws_size,
                              hipStream_t stream) {
    (void)in_sizes; (void)n_in;
    const float* enc = (const float*)d_in[0];
    const float* dec = (const float*)d_in[1];
    float* out = (float*)d_out;

    const size_t MLB = (size_t)NSPLIT * NB * TD * 4;      // 196,608 per array
    const size_t HB  = (size_t)NB * TE * DIM * 2;         // 8,388,608
    const size_t CSL = (size_t)NB * TD * DIM * 2;         // 8,388,608 per split

    float* m_arr = (float*)d_ws;
    float* l_arr = (float*)((char*)d_ws + MLB);
    f16*   ench  = (f16*)((char*)d_ws + 2 * MLB);
    f16*   ctxp  = (f16*)((char*)d_ws + 2 * MLB + HB);

    int nsplit;
    if      (ws_size >= 2 * MLB + HB + 3 * CSL) nsplit = 3;
    else if (ws_size >= 2 * MLB + HB + 2 * CSL) nsplit = 2;
    else { hipMemsetAsync(d_out, 0, (size_t)out_size * sizeof(float), stream); return; }

    prep_kernel<<<2048, 256, 0, stream>>>(enc, ench);
    attn_kernel<<<dim3(32, 8, nsplit), 256, 0, stream>>>(dec, ench, ctxp, m_arr, l_arr, nsplit);
    combine_kernel<<<2048, 256, 0, stream>>>(dec, ctxp, m_arr, l_arr, out, nsplit);
}